// Round 6
// baseline (345.114 us; speedup 1.0000x reference)
//
#include <hip/hip_runtime.h>
#include <hip/hip_bf16.h>
#include <math.h>

#define NN 32
#define CC 64
#define TT 256
#define VV 25
#define PAD 68     // old fused-path LDS stride
#define RS (VV * CC)          // 1600: (t,v)-row stride in elements, [n][t][v][c]
#define PERN (TT * VV * CC)   // 409600 elements per n

// k_proj LDS strides
#define XST 72     // shorts, X staging / S-transpose reuse (144B, 16B-aligned)
// k_attn LDS strides
#define VST2 72    // VT row stride (shorts)
#define PST 40     // P row stride (shorts)

typedef __attribute__((ext_vector_type(8))) short bf16x8;
typedef __attribute__((ext_vector_type(4))) float f32x4;

__device__ __forceinline__ float fast_tanh(float x) {
  float ax = fabsf(x);
  float e = __expf(-2.0f * ax);
  float r = 1.0f - 2.0f * e / (1.0f + e);
  return copysignf(r, x);
}
__device__ __forceinline__ unsigned short f2bf(float f) {   // RTN-even
  unsigned u = __float_as_uint(f);
  u += 0x7fff + ((u >> 16) & 1u);
  return (unsigned short)(u >> 16);
}
__device__ __forceinline__ float bf2f(unsigned short h) {
  return __uint_as_float(((unsigned)h) << 16);
}

__global__ void k0_zero(float* __restrict__ p) { p[threadIdx.x] = 0.0f; }

// ============================================================================
// k_wsplit: W -> bf16 hi/lo ([Wq|Wk|Wv] rows), bias concat, stats zero.
// ============================================================================
__global__ void k_wsplit(const float* __restrict__ Wq, const float* __restrict__ Wk,
                         const float* __restrict__ Wv, const float* __restrict__ bq,
                         const float* __restrict__ bk, const float* __restrict__ bv,
                         unsigned short* __restrict__ wh, unsigned short* __restrict__ wl,
                         float* __restrict__ bcat, float* __restrict__ stats)
{
  const int tid = threadIdx.x;
  if (tid < 128) stats[tid] = 0.0f;
  for (int i = 0; i < 48; ++i) {
    int idx = i * 256 + tid;               // < 12288 = 192*64
    int r = idx >> 6, c = idx & 63;
    int m = r >> 6, ch = r & 63;
    const float* W = (m == 0) ? Wq : (m == 1) ? Wk : Wv;
    float w = W[ch * 64 + c];
    unsigned short h = f2bf(w);
    wh[idx] = h;
    wl[idx] = f2bf(w - bf2f(h));
  }
  if (tid < 192) {
    int m = tid >> 6, ch = tid & 63;
    const float* B = (m == 0) ? bq : (m == 1) ? bk : bv;
    bcat[tid] = B[ch];
  }
}

// ============================================================================
// k_proj_mfma: GEMM [192][64] x [64][128tv]; outputs PRE-SPLIT bf16 planes
// qh,ql,kh,kl,vh in [n][t][v][c] (tv-contiguous rows -> coalesced stores).
// ============================================================================
__global__ __launch_bounds__(256, 2)
void k_proj_mfma(const float* __restrict__ x,
                 const unsigned short* __restrict__ wh,
                 const unsigned short* __restrict__ wl,
                 const float* __restrict__ bcat,
                 unsigned short* __restrict__ qh, unsigned short* __restrict__ ql,
                 unsigned short* __restrict__ kh, unsigned short* __restrict__ kl,
                 unsigned short* __restrict__ vh)
{
  __shared__ short Xbuf[2 * 128 * XST];    // X hi|lo; reused as S hi|lo (36,864 B)
  short* Xh = Xbuf;
  short* Xl = Xbuf + 128 * XST;

  const int tid  = threadIdx.x;
  const int lane = tid & 63;
  const int wid  = tid >> 6;
  const int l15  = lane & 15;
  const int g    = lane >> 4;
  const int band = wid * 48;               // wave's 48 D-rows

  const int n = blockIdx.x / 50;
  const int chunk = blockIdx.x - n * 50;
  const int tv0 = chunk * 128;
  const float* xn = x + (size_t)n * PERN + tv0;

  // ---- stage X: 64c x 128tv -> LDS bf16 hi/lo [tv][c]
  {
    const int cg  = tid >> 5;              // 0..7
    const int tvl = (tid & 31) * 4;
    #pragma unroll
    for (int r = 0; r < 2; ++r) {
      const int c0 = r * 32 + cg * 4;
      float4 r0 = *(const float4*)&xn[(size_t)(c0 + 0) * (TT * VV) + tvl];
      float4 r1 = *(const float4*)&xn[(size_t)(c0 + 1) * (TT * VV) + tvl];
      float4 r2 = *(const float4*)&xn[(size_t)(c0 + 2) * (TT * VV) + tvl];
      float4 r3 = *(const float4*)&xn[(size_t)(c0 + 3) * (TT * VV) + tvl];
      #pragma unroll
      for (int j = 0; j < 4; ++j) {
        float v0 = (&r0.x)[j], v1 = (&r1.x)[j], v2 = (&r2.x)[j], v3 = (&r3.x)[j];
        unsigned short h0 = f2bf(v0), h1 = f2bf(v1), h2 = f2bf(v2), h3 = f2bf(v3);
        *(short4*)&Xh[(tvl + j) * XST + c0] =
            make_short4((short)h0, (short)h1, (short)h2, (short)h3);
        *(short4*)&Xl[(tvl + j) * XST + c0] =
            make_short4((short)f2bf(v0 - bf2f(h0)), (short)f2bf(v1 - bf2f(h1)),
                        (short)f2bf(v2 - bf2f(h2)), (short)f2bf(v3 - bf2f(h3)));
      }
    }
  }

  // ---- W A-frags + bias
  bf16x8 wfh[3][2], wfl[3][2];
  #pragma unroll
  for (int rt = 0; rt < 3; ++rt)
    #pragma unroll
    for (int ks = 0; ks < 2; ++ks) {
      size_t off = (size_t)(band + rt * 16 + l15) * 64 + ks * 32 + g * 8;
      wfh[rt][ks] = *(const bf16x8*)&wh[off];
      wfl[rt][ks] = *(const bf16x8*)&wl[off];
    }
  float bc[3][4];
  #pragma unroll
  for (int rt = 0; rt < 3; ++rt)
    #pragma unroll
    for (int r = 0; r < 4; ++r)
      bc[rt][r] = bcat[band + rt * 16 + 4 * g + r];

  __syncthreads();

  // ---- MFMA
  f32x4 acc[3][8];
  #pragma unroll
  for (int rt = 0; rt < 3; ++rt)
    #pragma unroll
    for (int ct = 0; ct < 8; ++ct)
      acc[rt][ct] = (f32x4){0.f, 0.f, 0.f, 0.f};

  #pragma unroll
  for (int ct = 0; ct < 8; ++ct) {
    bf16x8 xh[2], xl[2];
    #pragma unroll
    for (int ks = 0; ks < 2; ++ks) {
      xh[ks] = *(const bf16x8*)&Xh[(ct * 16 + l15) * XST + ks * 32 + g * 8];
      xl[ks] = *(const bf16x8*)&Xl[(ct * 16 + l15) * XST + ks * 32 + g * 8];
    }
    #pragma unroll
    for (int rt = 0; rt < 3; ++rt)
      #pragma unroll
      for (int ks = 0; ks < 2; ++ks) {
        acc[rt][ct] = __builtin_amdgcn_mfma_f32_16x16x32_bf16(wfh[rt][ks], xh[ks], acc[rt][ct], 0, 0, 0);
        acc[rt][ct] = __builtin_amdgcn_mfma_f32_16x16x32_bf16(wfh[rt][ks], xl[ks], acc[rt][ct], 0, 0, 0);
        acc[rt][ct] = __builtin_amdgcn_mfma_f32_16x16x32_bf16(wfl[rt][ks], xh[ks], acc[rt][ct], 0, 0, 0);
      }
  }

  // ---- bias
  #pragma unroll
  for (int rt = 0; rt < 3; ++rt)
    #pragma unroll
    for (int ct = 0; ct < 8; ++ct)
      #pragma unroll
      for (int r = 0; r < 4; ++r)
        acc[rt][ct][r] += bc[rt][r];

  // ---- per matrix m: bf16 split + transpose via LDS, coalesced bf16x8 stores
  short* Sh = Xbuf;
  short* Sl = Xbuf + 128 * XST;
  const size_t cbase = ((size_t)n * (TT * VV) + tv0) * CC;   // shorts
  #pragma unroll
  for (int m = 0; m < 3; ++m) {
    __syncthreads();                       // prior reads of Xbuf/Sh/Sl done
    #pragma unroll
    for (int rt = 0; rt < 3; ++rt) {
      int grow = band + rt * 16;
      if ((grow >> 6) == m) {
        int ch = (grow & 63) + 4 * g;
        #pragma unroll
        for (int ct = 0; ct < 8; ++ct) {
          f32x4 a = acc[rt][ct];
          short4 h4, l4;
          #pragma unroll
          for (int r = 0; r < 4; ++r) {
            unsigned short h = f2bf(a[r]);
            (&h4.x)[r] = (short)h;
            (&l4.x)[r] = (short)f2bf(a[r] - bf2f(h));
          }
          *(short4*)&Sh[(ct * 16 + l15) * XST + ch] = h4;
          if (m < 2) *(short4*)&Sl[(ct * 16 + l15) * XST + ch] = l4;
        }
      }
    }
    __syncthreads();
    unsigned short* dh = (m == 0 ? qh : m == 1 ? kh : vh) + cbase;
    #pragma unroll
    for (int i = 0; i < 4; ++i) {
      int e = i * 256 + tid;               // 1024 x 8-short chunks
      *(bf16x8*)&dh[(size_t)e * 8] = *(const bf16x8*)&Sh[(e >> 3) * XST + (e & 7) * 8];
    }
    if (m < 2) {
      unsigned short* dl = (m == 0 ? ql : kl) + cbase;
      #pragma unroll
      for (int i = 0; i < 4; ++i) {
        int e = i * 256 + tid;
        *(bf16x8*)&dl[(size_t)e * 8] = *(const bf16x8*)&Sl[(e >> 3) * XST + (e & 7) * 8];
      }
    }
  }
}

// ============================================================================
// k_attn_mfma2: block = one (n,v); 4 waves x 64 q-rows.
// Swapped S (S^T = K.Q): D holds P^T -> P written as short4, read as B-frag.
// XOR-swizzled K/V tiles (conflict-free); V transposed by dedicated pass.
// PV single-term: O^T = Vh^T . Ph^T.  S 3-term hi/lo.
// ============================================================================
__global__ __launch_bounds__(256, 3)
void k_attn_mfma2(const unsigned short* __restrict__ qhp, const unsigned short* __restrict__ qlp,
                  const unsigned short* __restrict__ khp, const unsigned short* __restrict__ klp,
                  const unsigned short* __restrict__ vhp,
                  float* __restrict__ stats, float* __restrict__ ob)
{
  __shared__ short Kh[32 * 64], Kl[32 * 64], Vh[32 * 64];   // swizzled [t][blk^t&7]
  __shared__ short VT[64 * VST2];                           // V^T [c][t]
  __shared__ short Pw[4][64 * PST];                         // per-wave P[s][t]
  __shared__ float red1[256], red2[256];

  const int tid  = threadIdx.x;
  const int lane = tid & 63;
  const int wid  = tid >> 6;
  const int l15  = lane & 15;
  const int g    = lane >> 4;
  const int band = wid * 64;
  const int n = blockIdx.x / VV, v = blockIdx.x - n * VV;
  const size_t sbase = ((size_t)n * (TT * VV) + v) * CC;    // shorts; t-stride RS

  // ---- Q hi frags in regs; ql row pointers (reloaded per use, L2-hot)
  bf16x8 qhf[4][2];
  const unsigned short* qlrow[4];
  #pragma unroll
  for (int st = 0; st < 4; ++st) {
    const unsigned short* qp = qhp + sbase + (size_t)(band + st * 16 + l15) * RS + g * 8;
    qhf[st][0] = *(const bf16x8*)qp;
    qhf[st][1] = *(const bf16x8*)(qp + 32);
    qlrow[st] = qlp + sbase + (size_t)(band + st * 16 + l15) * RS + g * 8;
  }

  f32x4 acc[4][4];
  #pragma unroll
  for (int i = 0; i < 4; ++i)
    #pragma unroll
    for (int j = 0; j < 4; ++j)
      acc[i][j] = (f32x4){0.f, 0.f, 0.f, 0.f};

  // staging coords: thread -> (row sr, block scb); dest slot XOR-swizzled
  const int sr = tid >> 3, scb = tid & 7;
  const int swz = scb ^ (sr & 7);
  const size_t gsrc = sbase + (size_t)sr * RS + scb * 8;

  // prologue: stage tile 0
  {
    bf16x8 a = *(const bf16x8*)(khp + gsrc);
    bf16x8 b = *(const bf16x8*)(klp + gsrc);
    bf16x8 c = *(const bf16x8*)(vhp + gsrc);
    *(bf16x8*)&Kh[sr * 64 + swz * 8] = a;
    *(bf16x8*)&Kl[sr * 64 + swz * 8] = b;
    *(bf16x8*)&Vh[sr * 64 + swz * 8] = c;
  }

  const int slot0 = g ^ (l15 & 7);
  for (int tl = 0; tl < 8; ++tl) {
    __syncthreads();                       // staged K/V (this tile) visible
    bf16x8 nk_h, nk_l, nv_h;
    const bool more = (tl < 7);
    if (more) {                            // issue next-tile loads early
      const size_t src = gsrc + (size_t)(tl + 1) * 32 * RS;
      nk_h = *(const bf16x8*)(khp + src);
      nk_l = *(const bf16x8*)(klp + src);
      nv_h = *(const bf16x8*)(vhp + src);
    }

    // ---- S phase (swapped): D[t][s] = K.Q, 3-term; tanh; P[s][t] write
    #pragma unroll
    for (int rt = 0; rt < 2; ++rt) {
      const int rb = rt * 1024 + l15 * 64;
      bf16x8 kh0 = *(const bf16x8*)&Kh[rb + slot0 * 8];
      bf16x8 kh1 = *(const bf16x8*)&Kh[rb + (slot0 ^ 4) * 8];
      bf16x8 kl0 = *(const bf16x8*)&Kl[rb + slot0 * 8];
      bf16x8 kl1 = *(const bf16x8*)&Kl[rb + (slot0 ^ 4) * 8];
      #pragma unroll
      for (int st = 0; st < 4; ++st) {
        bf16x8 ql0 = *(const bf16x8*)(qlrow[st]);
        bf16x8 ql1 = *(const bf16x8*)(qlrow[st] + 32);
        f32x4 s = (f32x4){0.f, 0.f, 0.f, 0.f};
        s = __builtin_amdgcn_mfma_f32_16x16x32_bf16(kh0, qhf[st][0], s, 0, 0, 0);
        s = __builtin_amdgcn_mfma_f32_16x16x32_bf16(kh1, qhf[st][1], s, 0, 0, 0);
        s = __builtin_amdgcn_mfma_f32_16x16x32_bf16(kl0, qhf[st][0], s, 0, 0, 0);
        s = __builtin_amdgcn_mfma_f32_16x16x32_bf16(kl1, qhf[st][1], s, 0, 0, 0);
        s = __builtin_amdgcn_mfma_f32_16x16x32_bf16(kh0, ql0, s, 0, 0, 0);
        s = __builtin_amdgcn_mfma_f32_16x16x32_bf16(kh1, ql1, s, 0, 0, 0);
        short4 h4;
        #pragma unroll
        for (int r = 0; r < 4; ++r) {
          float p = fast_tanh(s[r] * 0.125f);
          (&h4.x)[r] = (short)f2bf(p);
        }
        // P[s = st*16+l15][t = rt*16+4g .. +3]
        *(short4*)&Pw[wid][(st * 16 + l15) * PST + rt * 16 + 4 * g] = h4;
      }
    }

    // ---- VT pass: V[t][c] -> VT[c][t] (column reads 2/bank, b128 writes)
    {
      const int c = tid & 63, b = tid >> 6;
      bf16x8 colv;
      #pragma unroll
      for (int e = 0; e < 8; ++e) {
        int t = 8 * b + e;
        colv[e] = Vh[t * 64 + (((c >> 3) ^ (t & 7)) * 8) + (c & 7)];
      }
      *(bf16x8*)&VT[c * VST2 + 8 * b] = colv;
    }
    __syncthreads();                       // VT visible (P is per-wave)

    // ---- PV: O^T += Vh^T . Ph^T  (16 MFMA)
    bf16x8 vtf[4], pf[4];
    #pragma unroll
    for (int i = 0; i < 4; ++i) {
      vtf[i] = *(const bf16x8*)&VT[(i * 16 + l15) * VST2 + g * 8];
      pf[i]  = *(const bf16x8*)&Pw[wid][(i * 16 + l15) * PST + g * 8];
    }
    #pragma unroll
    for (int ctc = 0; ctc < 4; ++ctc)
      #pragma unroll
      for (int st = 0; st < 4; ++st)
        acc[ctc][st] = __builtin_amdgcn_mfma_f32_16x16x32_bf16(vtf[ctc], pf[st], acc[ctc][st], 0, 0, 0);

    // ---- write-late staging (safe: K/V reads for this tile all done)
    if (more) {
      *(bf16x8*)&Kh[sr * 64 + swz * 8] = nk_h;
      *(bf16x8*)&Kl[sr * 64 + swz * 8] = nk_l;
      *(bf16x8*)&Vh[sr * 64 + swz * 8] = nv_h;
    }
  }

  // ---- LN partial sums (acc layout identical to R5: O^T[c][s])
  #pragma unroll
  for (int ctc = 0; ctc < 4; ++ctc) {
    #pragma unroll
    for (int r = 0; r < 4; ++r) {
      float s1 = 0.f, s2 = 0.f;
      #pragma unroll
      for (int st = 0; st < 4; ++st) { float vv = acc[ctc][st][r]; s1 += vv; s2 += vv * vv; }
      #pragma unroll
      for (int m = 1; m <= 8; m <<= 1) {
        s1 += __shfl_xor(s1, m, 64);
        s2 += __shfl_xor(s2, m, 64);
      }
      if (l15 == 0) {
        int c = ctc * 16 + 4 * g + r;
        red1[wid * 64 + c] = s1;
        red2[wid * 64 + c] = s2;
      }
    }
  }
  __syncthreads();
  if (tid < 64) {
    float a1 = red1[tid] + red1[64 + tid] + red1[128 + tid] + red1[192 + tid];
    float a2 = red2[tid] + red2[64 + tid] + red2[128 + tid] + red2[192 + tid];
    atomicAdd(&stats[tid], a1);
    atomicAdd(&stats[64 + tid], a2);
  }

  // ---- store pre-LN O to ob[n][t][v][c] (fp32)
  float* obp = (float*)ob + sbase;
  #pragma unroll
  for (int st = 0; st < 4; ++st)
    #pragma unroll
    for (int ctc = 0; ctc < 4; ++ctc)
      *(f32x4*)&obp[(size_t)(band + st * 16 + l15) * RS + ctc * 16 + 4 * g] = acc[ctc][st];
}

// ============================================================================
// Epilogue
// ============================================================================
__global__ void k2_stats(const float* __restrict__ stats,
                         const float* __restrict__ gamma,
                         const float* __restrict__ beta,
                         float* __restrict__ ss)
{
  int c = threadIdx.x;
  if (c < 64) {
    const float M = (float)(NN * TT * VV);
    float mean = stats[c] / M;
    float var = stats[64 + c] / M - mean * mean;
    float sc = gamma[c] * rsqrtf(var + 1e-5f);
    ss[c] = sc;
    ss[64 + c] = beta[c] - mean * sc;
  }
}

__global__ __launch_bounds__(256)
void k3_emit(const float* __restrict__ ob, const float* __restrict__ ss,
             float* __restrict__ out)
{
  __shared__ float tile[VV * 8 * 65];
  __shared__ float scl[64], sft[64];
  const int bid = blockIdx.x;
  const int n = bid >> 5, sb = bid & 31;
  const int tid = threadIdx.x;
  if (tid < 64) { scl[tid] = ss[tid]; sft[tid] = ss[64 + tid]; }
  const float* src = ob + (size_t)n * PERN + (size_t)sb * 8 * RS;
  #pragma unroll
  for (int i = 0; i < 25; ++i) {
    int e2 = i * 512 + tid * 2;
    float2 f = *(const float2*)&src[e2];
    int c = e2 & 63;
    int r = e2 >> 6;
    int tL = r / 25, vv2 = r - tL * 25;
    tile[(vv2 * 8 + tL) * 65 + c] = f.x;
    tile[(vv2 * 8 + tL) * 65 + c + 1] = f.y;
  }
  __syncthreads();
  float* outn = out + (size_t)n * CC * TT * VV + sb * 8 * VV;
  for (int e = tid; e < CC * 200; e += 256) {
    int c = e / 200, r = e - c * 200;
    int tL = r / 25, v = r - tL * 25;
    float val = tile[(v * 8 + tL) * 65 + c];
    outn[(size_t)c * TT * VV + tL * VV + v] = val * scl[c] + sft[c];
  }
}

__global__ void k3b_inplace(float* __restrict__ out, const float* __restrict__ ss) {
  __shared__ float scl[64], sft[64];
  if (threadIdx.x < 64) { scl[threadIdx.x] = ss[threadIdx.x]; sft[threadIdx.x] = ss[64 + threadIdx.x]; }
  __syncthreads();
  const size_t total = (size_t)NN * CC * TT * VV;
  size_t i = ((size_t)blockIdx.x * 256 + threadIdx.x) * 4;
  const size_t stride = (size_t)gridDim.x * 256 * 4;
  for (; i < total; i += stride) {
    float4 val = *(float4*)(out + i);
    int c = (int)((i / (TT * VV)) & 63);
    val.x = val.x * scl[c] + sft[c];
    val.y = val.y * scl[c] + sft[c];
    val.z = val.z * scl[c] + sft[c];
    val.w = val.w * scl[c] + sft[c];
    *(float4*)(out + i) = val;
  }
}

// ============================================================================
// Path C fallback: round-1 fused kernel (known-correct, small-ws only)
// ============================================================================
__device__ __forceinline__ void proj_row(const float* xs, const float* Wl,
                                         const float* bl, float* dst) {
  for (int d4 = 0; d4 < 16; ++d4) {
    float4 r;
    #pragma unroll
    for (int j = 0; j < 4; ++j) {
      const int d = d4 * 4 + j;
      float acc = bl[d];
      #pragma unroll
      for (int c = 0; c < CC; ++c) acc += xs[c] * Wl[d * CC + c];
      ((float*)&r)[j] = acc;
    }
    *(float4*)&dst[d4 * 4] = r;
  }
}

__global__ __launch_bounds__(256)
void k1_attn(const float* __restrict__ x,
             const float* __restrict__ Wq, const float* __restrict__ bq,
             const float* __restrict__ Wk, const float* __restrict__ bk,
             const float* __restrict__ Wv, const float* __restrict__ bv,
             float* __restrict__ stats, float* __restrict__ outbuf)
{
  __shared__ float kl[TT * PAD];
  __shared__ float vl[TT * PAD];
  __shared__ float Wl[CC * CC];
  __shared__ float bl[CC];
  const int tid = threadIdx.x;
  const int bid = blockIdx.x;
  const int n = bid / VV, v = bid - n * VV;
  float xs[CC];
  {
    const float* xp = x + ((size_t)n * CC * TT + tid) * VV + v;
    #pragma unroll
    for (int c = 0; c < CC; ++c) xs[c] = xp[(size_t)c * TT * VV];
  }
  {
    const float4* Wg = (const float4*)Wq;
    float4* Wd = (float4*)Wl;
    #pragma unroll
    for (int j = 0; j < 4; ++j) Wd[j * 256 + tid] = Wg[j * 256 + tid];
    if (tid < CC) bl[tid] = bq[tid];
    __syncthreads();
    proj_row(xs, Wl, bl, &kl[tid * PAD]);
  }
  float q[CC];
  #pragma unroll
  for (int c4 = 0; c4 < 16; ++c4) {
    float4 t4 = *(const float4*)&kl[tid * PAD + c4 * 4];
    q[c4 * 4 + 0] = t4.x; q[c4 * 4 + 1] = t4.y;
    q[c4 * 4 + 2] = t4.z; q[c4 * 4 + 3] = t4.w;
  }
  __syncthreads();
  {
    const float4* Wg = (const float4*)Wk;
    float4* Wd = (float4*)Wl;
    #pragma unroll
    for (int j = 0; j < 4; ++j) Wd[j * 256 + tid] = Wg[j * 256 + tid];
    if (tid < CC) bl[tid] = bk[tid];
    __syncthreads();
    proj_row(xs, Wl, bl, &kl[tid * PAD]);
    __syncthreads();
  }
  {
    const float4* Wg = (const float4*)Wv;
    float4* Wd = (float4*)Wl;
    #pragma unroll
    for (int j = 0; j < 4; ++j) Wd[j * 256 + tid] = Wg[j * 256 + tid];
    if (tid < CC) bl[tid] = bv[tid];
    __syncthreads();
    proj_row(xs, Wl, bl, &vl[tid * PAD]);
    __syncthreads();
  }
  float out[CC];
  #pragma unroll
  for (int c = 0; c < CC; ++c) out[c] = 0.0f;
  for (int t = 0; t < TT; ++t) {
    const float4* kr = (const float4*)&kl[t * PAD];
    float acc = 0.0f;
    #pragma unroll
    for (int c4 = 0; c4 < 16; ++c4) {
      float4 kk = kr[c4];
      acc += q[c4 * 4 + 0] * kk.x + q[c4 * 4 + 1] * kk.y
           + q[c4 * 4 + 2] * kk.z + q[c4 * 4 + 3] * kk.w;
    }
    float a = fast_tanh(acc * 0.125f);
    const float4* vr = (const float4*)&vl[t * PAD];
    #pragma unroll
    for (int c4 = 0; c4 < 16; ++c4) {
      float4 vv = vr[c4];
      out[c4 * 4 + 0] += a * vv.x; out[c4 * 4 + 1] += a * vv.y;
      out[c4 * 4 + 2] += a * vv.z; out[c4 * 4 + 3] += a * vv.w;
    }
  }
  __syncthreads();
  float* out_lds = vl;
  #pragma unroll
  for (int c4 = 0; c4 < 16; ++c4) {
    *(float4*)&out_lds[tid * PAD + c4 * 4] =
        make_float4(out[c4 * 4 + 0], out[c4 * 4 + 1], out[c4 * 4 + 2], out[c4 * 4 + 3]);
  }
  __syncthreads();
  {
    const int c = tid & 63, gg = tid >> 6;
    float s1 = 0.0f, s2 = 0.0f;
    for (int s = gg * 64; s < gg * 64 + 64; ++s) {
      float val = out_lds[s * PAD + c];
      s1 += val; s2 += val * val;
    }
    float* part = Wl;
    part[tid] = s1;
    part[256 + tid] = s2;
    __syncthreads();
    if (tid < 64) {
      float a1 = part[tid] + part[64 + tid] + part[128 + tid] + part[192 + tid];
      float a2 = part[256 + tid] + part[320 + tid] + part[384 + tid] + part[448 + tid];
      atomicAdd(&stats[tid], a1);
      atomicAdd(&stats[64 + tid], a2);
    }
  }
  {
    float* obp = outbuf + (size_t)n * CC * TT * VV + v;
    for (int e = tid; e < TT * CC; e += 256) {
      int s = e >> 6, c = e & 63;
      obp[(size_t)c * TT * VV + (size_t)s * VV] = out_lds[s * PAD + c];
    }
  }
}

// ============================================================================

extern "C" void kernel_launch(void* const* d_in, const int* in_sizes, int n_in,
                              void* d_out, int out_size, void* d_ws, size_t ws_size,
                              hipStream_t stream) {
  (void)in_sizes; (void)n_in; (void)out_size;
  const float* x     = (const float*)d_in[0];
  const float* Wq    = (const float*)d_in[1];
  const float* bq    = (const float*)d_in[2];
  const float* Wk    = (const float*)d_in[3];
  const float* bk    = (const float*)d_in[4];
  const float* Wv    = (const float*)d_in[5];
  const float* bv    = (const float*)d_in[6];
  const float* gamma = (const float*)d_in[7];
  const float* beta  = (const float*)d_in[8];
  float* out = (float*)d_out;
  float* wsf = (float*)d_ws;

  // ws map: [stats 128][ss 128][bcat 256][wh|wl 24576 ush][5 bf16 planes][ob f32]
  float* stats = wsf;
  float* ss    = wsf + 128;
  float* bcat  = wsf + 256;
  unsigned short* wh = (unsigned short*)(wsf + 512);
  unsigned short* wl = wh + 192 * 64;
  const size_t PS = (size_t)NN * PERN;                      // elements/plane
  unsigned short* qh = (unsigned short*)(wsf + 512 + 12288);
  unsigned short* ql = qh + PS;
  unsigned short* kh = ql + PS;
  unsigned short* kl = kh + PS;
  unsigned short* vh = kl + PS;
  float* ob = (float*)(vh + PS);
  const size_t need = (size_t)(512 + 12288) * 4 + 5 * PS * 2 + PS * 4;

  if (ws_size >= need) {
    k_wsplit<<<1, 256, 0, stream>>>(Wq, Wk, Wv, bq, bk, bv, wh, wl, bcat, stats);
    k_proj_mfma<<<NN * 50, 256, 0, stream>>>(x, wh, wl, bcat, qh, ql, kh, kl, vh);
    k_attn_mfma2<<<NN * VV, 256, 0, stream>>>(qh, ql, kh, kl, vh, stats, ob);
    k2_stats<<<1, 64, 0, stream>>>(stats, gamma, beta, ss);
    k3_emit<<<NN * 32, 256, 0, stream>>>(ob, ss, out);
  } else {
    k0_zero<<<1, 128, 0, stream>>>(stats);
    k1_attn<<<NN * VV, 256, 0, stream>>>(x, Wq, bq, Wk, bk, Wv, bv, stats, out);
    k2_stats<<<1, 64, 0, stream>>>(stats, gamma, beta, ss);
    k3b_inplace<<<2048, 256, 0, stream>>>(out, ss);
  }
}